// Round 1
// baseline (723.607 us; speedup 1.0000x reference)
//
#include <hip/hip_runtime.h>

// Problem constants
#define BS 6
#define NQ 4096
#define NH 8
#define NL 4
#define NP 8
#define EMB 256
#define LTOT 19560
#define ROWS_V (BS * LTOT)   // 117360
#define ROWS_Q (BS * NQ)     // 24576

// Workspace layout (bytes)
#define V_BYTES    ((size_t)ROWS_V * EMB * 4)          // 120,176,640
#define OFF_BYTES  ((size_t)ROWS_Q * 512 * 4)          // 50,331,648
#define ATTN_BYTES ((size_t)ROWS_Q * EMB * 4)          // 25,165,824
#define AGG_BYTES  ((size_t)ROWS_Q * EMB * 4)

#define FMA4(d, s, v) \
    (d).x = fmaf((s), (v).x, (d).x); \
    (d).y = fmaf((s), (v).y, (d).y); \
    (d).z = fmaf((s), (v).z, (d).z); \
    (d).w = fmaf((s), (v).w, (d).w);

// ---------------------------------------------------------------------------
// fp32 tiled GEMM: C[M,N] = A[M,K=256] @ B[256,N] + bias[N]
// 128x128 tile, BK=8, 256 threads, each thread 8x8 as 2x2 blocks of 4x4.
// N must be a multiple of 128; M guarded.
// ---------------------------------------------------------------------------
__global__ __launch_bounds__(256) void gemm128(
    const float* __restrict__ A, const float* __restrict__ B,
    const float* __restrict__ bias, float* __restrict__ C,
    int M, int N)
{
    constexpr int K = 256;
    __shared__ float As[8][128];
    __shared__ float Bs[8][128];

    const int t  = threadIdx.x;
    const int bm = blockIdx.x * 128;
    const int bn = blockIdx.y * 128;
    const int tx = t & 15;
    const int ty = t >> 4;

    // A staging: each thread loads one float4 along K
    const int arow = t >> 1;          // 0..127
    const int akv  = (t & 1) * 4;     // 0 or 4
    // B staging: each thread loads one float4 along N
    const int brow = t >> 5;          // 0..7
    const int bcol = (t & 31) * 4;    // 0..124

    const bool arowok = (bm + arow) < M;
    const float* Aptr = A + (size_t)(bm + arow) * K + akv;
    const float* Bptr = B + (size_t)brow * N + bn + bcol;

    float4 acc[2][2][4];
    #pragma unroll
    for (int i = 0; i < 2; ++i)
        #pragma unroll
        for (int j = 0; j < 2; ++j)
            #pragma unroll
            for (int e = 0; e < 4; ++e)
                acc[i][j][e] = make_float4(0.f, 0.f, 0.f, 0.f);

    for (int kt = 0; kt < K; kt += 8) {
        float4 af = arowok ? *(const float4*)(Aptr + kt)
                           : make_float4(0.f, 0.f, 0.f, 0.f);
        float4 bf = *(const float4*)(Bptr + (size_t)kt * N);

        __syncthreads();
        As[akv + 0][arow] = af.x;
        As[akv + 1][arow] = af.y;
        As[akv + 2][arow] = af.z;
        As[akv + 3][arow] = af.w;
        *(float4*)&Bs[brow][bcol] = bf;
        __syncthreads();

        #pragma unroll
        for (int k = 0; k < 8; ++k) {
            float4 a0 = *(const float4*)&As[k][ty * 4];
            float4 a1 = *(const float4*)&As[k][ty * 4 + 64];
            float4 b0 = *(const float4*)&Bs[k][tx * 4];
            float4 b1 = *(const float4*)&Bs[k][tx * 4 + 64];
            float ar[8] = {a0.x, a0.y, a0.z, a0.w, a1.x, a1.y, a1.z, a1.w};
            #pragma unroll
            for (int i = 0; i < 2; ++i) {
                #pragma unroll
                for (int e = 0; e < 4; ++e) {
                    float a = ar[i * 4 + e];
                    FMA4(acc[i][0][e], a, b0);
                    FMA4(acc[i][1][e], a, b1);
                }
            }
        }
    }

    float4 bias0 = *(const float4*)(bias + bn + tx * 4);
    float4 bias1 = *(const float4*)(bias + bn + 64 + tx * 4);

    #pragma unroll
    for (int i = 0; i < 2; ++i) {
        #pragma unroll
        for (int e = 0; e < 4; ++e) {
            int row = bm + i * 64 + ty * 4 + e;
            if (row < M) {
                float4 r0 = acc[i][0][e];
                r0.x += bias0.x; r0.y += bias0.y; r0.z += bias0.z; r0.w += bias0.w;
                *(float4*)(C + (size_t)row * N + bn + tx * 4) = r0;
                float4 r1 = acc[i][1][e];
                r1.x += bias1.x; r1.y += bias1.y; r1.z += bias1.z; r1.w += bias1.w;
                *(float4*)(C + (size_t)row * N + bn + 64 + tx * 4) = r1;
            }
        }
    }
}

// ---------------------------------------------------------------------------
// softmax over rows of 32 (in-place capable)
// ---------------------------------------------------------------------------
__global__ __launch_bounds__(256) void softmax32(
    const float* __restrict__ in, float* __restrict__ out, int rows)
{
    int r = blockIdx.x * blockDim.x + threadIdx.x;
    if (r >= rows) return;
    const float* p = in + (size_t)r * 32;
    float v[32];
    #pragma unroll
    for (int i = 0; i < 8; ++i)
        *(float4*)&v[i * 4] = *(const float4*)(p + i * 4);
    float m = v[0];
    #pragma unroll
    for (int i = 1; i < 32; ++i) m = fmaxf(m, v[i]);
    float s = 0.f;
    #pragma unroll
    for (int i = 0; i < 32; ++i) { v[i] = __expf(v[i] - m); s += v[i]; }
    float inv = 1.f / s;
    float* q = out + (size_t)r * 32;
    #pragma unroll
    for (int i = 0; i < 8; ++i) {
        float4 w = make_float4(v[i*4] * inv, v[i*4+1] * inv, v[i*4+2] * inv, v[i*4+3] * inv);
        *(float4*)(q + i * 4) = w;
    }
}

// ---------------------------------------------------------------------------
// Deformable sampling + aggregation.
// 8 threads per (b,q,h); thread st owns channels [st*4, st*4+4) and points
// [st*4, st*4+4) for broadcast. 32 points = 4 levels x 8 points.
// v layout: (b, loc, h*32+dd). agg layout: (b, q, h*32+dd).
// ---------------------------------------------------------------------------
__global__ __launch_bounds__(256) void sampler(
    const float* __restrict__ v,      // (BS, LTOT, 256)
    const float* __restrict__ off,    // (BS, NQ, 8, 4, 8, 2)
    const float* __restrict__ aw,     // (BS, NQ, 8, 32) softmaxed
    const float* __restrict__ ref,    // (BS, NQ, 4, 2)
    float* __restrict__ agg)          // (BS, NQ, 256)
{
    const int tid = threadIdx.x;
    const int g = blockIdx.x * 32 + (tid >> 3);   // (b*NQ+q)*8 + h
    const int st = tid & 7;
    const int h = g & 7;
    const int bq = g >> 3;
    const int b = bq >> 12;   // NQ = 4096

    // this thread's 4 points: offsets (x,y interleaved) and attention weights
    float o[8];
    {
        const float* offp = off + (size_t)bq * 512 + h * 64 + st * 8;
        float4 f1 = *(const float4*)(offp);
        float4 f2 = *(const float4*)(offp + 4);
        o[0] = f1.x; o[1] = f1.y; o[2] = f1.z; o[3] = f1.w;
        o[4] = f2.x; o[5] = f2.y; o[6] = f2.z; o[7] = f2.w;
    }
    float a4[4];
    {
        float4 f = *(const float4*)(aw + (size_t)bq * 256 + h * 32 + st * 4);
        a4[0] = f.x; a4[1] = f.y; a4[2] = f.z; a4[3] = f.w;
    }
    float rf[8];
    {
        float4 f1 = *(const float4*)(ref + (size_t)bq * 8);
        float4 f2 = *(const float4*)(ref + (size_t)bq * 8 + 4);
        rf[0] = f1.x; rf[1] = f1.y; rf[2] = f1.z; rf[3] = f1.w;
        rf[4] = f2.x; rf[5] = f2.y; rf[6] = f2.z; rf[7] = f2.w;
    }

    const float* vb = v + (size_t)b * LTOT * EMB + h * 32 + st * 4;

    const int LW[4] = {160, 80, 40, 20};
    const int LH[4] = {92, 46, 23, 12};
    const int LS[4] = {0, 14720, 18400, 19320};

    float4 acc = make_float4(0.f, 0.f, 0.f, 0.f);

    #pragma unroll
    for (int k = 0; k < 32; ++k) {
        const int l = k >> 3;
        const int W = LW[l], Hh = LH[l], S = LS[l];
        const int src = k >> 2;
        const int idx = k & 3;
        float awk = __shfl(a4[idx], src, 8);
        float ox  = __shfl(o[2 * idx], src, 8);
        float oy  = __shfl(o[2 * idx + 1], src, 8);

        float px = fmaf(rf[2 * l], (float)W, ox) - 0.5f;
        float py = fmaf(rf[2 * l + 1], (float)Hh, oy) - 0.5f;
        float x0f = floorf(px), y0f = floorf(py);
        float wx = px - x0f, wy = py - y0f;
        int x0 = (int)x0f, y0 = (int)y0f;
        int x1 = x0 + 1, y1 = y0 + 1;

        float vx0 = (x0 >= 0 && x0 < W) ? 1.f : 0.f;
        float vx1 = (x1 >= 0 && x1 < W) ? 1.f : 0.f;
        float vy0 = (y0 >= 0 && y0 < Hh) ? 1.f : 0.f;
        float vy1 = (y1 >= 0 && y1 < Hh) ? 1.f : 0.f;
        int cx0 = min(max(x0, 0), W - 1);
        int cx1 = min(max(x1, 0), W - 1);
        int cy0 = min(max(y0, 0), Hh - 1);
        int cy1 = min(max(y1, 0), Hh - 1);

        float w00 = (1.f - wx) * (1.f - wy) * vx0 * vy0 * awk;
        float w10 = wx * (1.f - wy) * vx1 * vy0 * awk;
        float w01 = (1.f - wx) * wy * vx0 * vy1 * awk;
        float w11 = wx * wy * vx1 * vy1 * awk;

        const float* p00 = vb + (size_t)(S + cy0 * W + cx0) * EMB;
        const float* p10 = vb + (size_t)(S + cy0 * W + cx1) * EMB;
        const float* p01 = vb + (size_t)(S + cy1 * W + cx0) * EMB;
        const float* p11 = vb + (size_t)(S + cy1 * W + cx1) * EMB;
        float4 c00 = *(const float4*)p00;
        float4 c10 = *(const float4*)p10;
        float4 c01 = *(const float4*)p01;
        float4 c11 = *(const float4*)p11;

        FMA4(acc, w00, c00);
        FMA4(acc, w10, c10);
        FMA4(acc, w01, c01);
        FMA4(acc, w11, c11);
    }

    *(float4*)(agg + (size_t)bq * 256 + h * 32 + st * 4) = acc;
}

// ---------------------------------------------------------------------------
// Launch
// ---------------------------------------------------------------------------
extern "C" void kernel_launch(void* const* d_in, const int* in_sizes, int n_in,
                              void* d_out, int out_size, void* d_ws, size_t ws_size,
                              hipStream_t stream) {
    const float* query  = (const float*)d_in[0];
    const float* value  = (const float*)d_in[1];
    const float* refpts = (const float*)d_in[2];
    // d_in[3] = spatial_shapes (int32) — hardcoded
    const float* W_off  = (const float*)d_in[4];
    const float* b_off  = (const float*)d_in[5];
    const float* W_attn = (const float*)d_in[6];
    const float* b_attn = (const float*)d_in[7];
    const float* W_val  = (const float*)d_in[8];
    const float* b_val  = (const float*)d_in[9];
    const float* W_out  = (const float*)d_in[10];
    const float* b_out  = (const float*)d_in[11];
    float* out = (float*)d_out;

    char* ws = (char*)d_ws;
    float* v_buf    = (float*)(ws);
    float* off_buf  = (float*)(ws + V_BYTES);
    float* attn_buf = (float*)(ws + V_BYTES + OFF_BYTES);
    float* agg_buf  = (float*)(ws + V_BYTES + OFF_BYTES + ATTN_BYTES);

    // 1. v = value @ W_val + b_val   (117360 x 256)
    gemm128<<<dim3((ROWS_V + 127) / 128, EMB / 128), 256, 0, stream>>>(
        value, W_val, b_val, v_buf, ROWS_V, EMB);

    // 2a. off = query @ W_off + b_off   (24576 x 512)
    gemm128<<<dim3(ROWS_Q / 128, 512 / 128), 256, 0, stream>>>(
        query, W_off, b_off, off_buf, ROWS_Q, 512);

    // 2b. attn logits = query @ W_attn + b_attn   (24576 x 256)
    gemm128<<<dim3(ROWS_Q / 128, EMB / 128), 256, 0, stream>>>(
        query, W_attn, b_attn, attn_buf, ROWS_Q, EMB);

    // 3. softmax over 32 per (b,q,h)
    softmax32<<<(ROWS_Q * NH + 255) / 256, 256, 0, stream>>>(
        attn_buf, attn_buf, ROWS_Q * NH);

    // 4. deformable sampling + aggregation
    sampler<<<(ROWS_Q * NH) / 32, 256, 0, stream>>>(
        v_buf, off_buf, attn_buf, refpts, agg_buf);

    // 5. out = agg @ W_out + b_out   (24576 x 256)
    gemm128<<<dim3(ROWS_Q / 128, EMB / 128), 256, 0, stream>>>(
        agg_buf, W_out, b_out, out, ROWS_Q, EMB);
}

// Round 2
// 483.010 us; speedup vs baseline: 1.4981x; 1.4981x over previous
//
#include <hip/hip_runtime.h>
#include <stdint.h>

// Problem constants
#define BS 6
#define NQ 4096
#define NH 8
#define EMB 256
#define LTOT 19560
#define ROWS_V 117360
#define ROWS_VP 117376          // padded to 917*128
#define ROWS_Q 24576            // 192*128

typedef __attribute__((ext_vector_type(8))) short bf16x8;
typedef __attribute__((ext_vector_type(4))) float floatx4;

__device__ __forceinline__ ushort f2bf(float f) {
    union { float f; uint32_t i; } c; c.f = f;
    uint32_t r = c.i + 0x7FFFu + ((c.i >> 16) & 1u);   // round-to-nearest-even
    return (ushort)(r >> 16);
}
__device__ __forceinline__ float bflo(uint32_t u) {
    union { uint32_t i; float f; } c; c.i = u << 16; return c.f;
}
__device__ __forceinline__ float bfhi(uint32_t u) {
    union { uint32_t i; float f; } c; c.i = u & 0xFFFF0000u; return c.f;
}

__device__ __forceinline__ void gll16(const ushort* g, ushort* l) {
    __builtin_amdgcn_global_load_lds(
        (const __attribute__((address_space(1))) void*)g,
        (__attribute__((address_space(3))) void*)l, 16, 0, 0);
}

#define FMA4(d, s, v) \
    (d).x = fmaf((s), (v).x, (d).x); \
    (d).y = fmaf((s), (v).y, (d).y); \
    (d).z = fmaf((s), (v).z, (d).z); \
    (d).w = fmaf((s), (v).w, (d).w);

// ---------------------------------------------------------------------------
// fp32 -> bf16 cast, 8 elems/thread; zero-fills padding region [n, n_pad)
// ---------------------------------------------------------------------------
__global__ __launch_bounds__(256) void cast_bf16(
    const float* __restrict__ in, ushort* __restrict__ out, int n, int n_pad)
{
    int i = (blockIdx.x * 256 + threadIdx.x) * 8;
    if (i >= n_pad) return;
    ushort4 r0, r1;
    if (i < n) {   // n is a multiple of 8
        float4 f0 = *(const float4*)(in + i);
        float4 f1 = *(const float4*)(in + i + 4);
        r0.x = f2bf(f0.x); r0.y = f2bf(f0.y); r0.z = f2bf(f0.z); r0.w = f2bf(f0.w);
        r1.x = f2bf(f1.x); r1.y = f2bf(f1.y); r1.z = f2bf(f1.z); r1.w = f2bf(f1.w);
    } else {
        r0.x = r0.y = r0.z = r0.w = 0;
        r1 = r0;
    }
    *(ushort4*)(out + i) = r0;
    *(ushort4*)(out + i + 4) = r1;
}

// ---------------------------------------------------------------------------
// W (K x N) fp32  ->  Wt (N x K) bf16   (tiny matrices, naive)
// ---------------------------------------------------------------------------
__global__ __launch_bounds__(256) void cast_t(
    const float* __restrict__ W, ushort* __restrict__ Wt, int N_)
{
    int id = blockIdx.x * 256 + threadIdx.x;
    if (id >= 256 * N_) return;
    int n = id >> 8;         // / 256 (K = 256)
    int k = id & 255;
    Wt[id] = f2bf(W[(size_t)k * N_ + n]);
}

// ---------------------------------------------------------------------------
// bf16 MFMA GEMM (m97 structure): C[M,N] = A[M,256] @ Bt[N,256]^T + bias
// 128x128 tile, BK=32, 256 threads = 4 waves (2x2 of 64x64), 16x16x32 MFMA.
// A must be padded to a multiple of 128 rows; store guarded by M.
// ---------------------------------------------------------------------------
template<bool OUT_BF16>
__global__ __launch_bounds__(256) void gemm_bt(
    const ushort* __restrict__ A,    // Mpad x 256 bf16
    const ushort* __restrict__ Bt,   // N x 256 bf16
    const float* __restrict__ bias,  // N
    void* __restrict__ Cv, int M, int N)
{
    constexpr int K = 256;
    __shared__ ushort As[128 * 32];
    __shared__ ushort Bs[128 * 32];

    const int t = threadIdx.x;
    const int w = t >> 6;
    const int lane = t & 63;
    const int bm = blockIdx.x * 128;
    const int bn = blockIdx.y * 128;
    const int wm = (w >> 1) * 64;
    const int wn = (w & 1) * 64;

    floatx4 acc[4][4] = {};

    // staging: wave w stages chunks 2w, 2w+1; chunk = 16 rows x 32 k (1 KiB)
    const int srow = lane >> 2;
    const int scol = (lane & 3) * 8;
    const ushort* Ag0 = A + (size_t)(bm + (w * 2 + 0) * 16 + srow) * K + scol;
    const ushort* Ag1 = A + (size_t)(bm + (w * 2 + 1) * 16 + srow) * K + scol;
    const ushort* Bg0 = Bt + (size_t)(bn + (w * 2 + 0) * 16 + srow) * K + scol;
    const ushort* Bg1 = Bt + (size_t)(bn + (w * 2 + 1) * 16 + srow) * K + scol;
    ushort* Al0 = &As[(w * 2 + 0) * 512];
    ushort* Al1 = &As[(w * 2 + 1) * 512];
    ushort* Bl0 = &Bs[(w * 2 + 0) * 512];
    ushort* Bl1 = &Bs[(w * 2 + 1) * 512];

    const ushort* apt = &As[(wm + (lane & 15)) * 32 + (lane >> 4) * 8];
    const ushort* bpt = &Bs[(wn + (lane & 15)) * 32 + (lane >> 4) * 8];

    for (int kt = 0; kt < K; kt += 32) {
        __syncthreads();
        gll16(Ag0 + kt, Al0);
        gll16(Ag1 + kt, Al1);
        gll16(Bg0 + kt, Bl0);
        gll16(Bg1 + kt, Bl1);
        __syncthreads();

        bf16x8 a[4], b[4];
        #pragma unroll
        for (int i = 0; i < 4; ++i) {
            a[i] = *(const bf16x8*)(apt + i * 16 * 32);
            b[i] = *(const bf16x8*)(bpt + i * 16 * 32);
        }
        #pragma unroll
        for (int i = 0; i < 4; ++i)
            #pragma unroll
            for (int j = 0; j < 4; ++j)
                acc[i][j] = __builtin_amdgcn_mfma_f32_16x16x32_bf16(
                    a[i], b[j], acc[i][j], 0, 0, 0);
    }

    // epilogue: C/D layout col = lane&15, row = (lane>>4)*4 + reg
    const int crow = (lane >> 4) * 4;
    const int ccol = lane & 15;
    #pragma unroll
    for (int j = 0; j < 4; ++j) {
        int gcol = bn + wn + j * 16 + ccol;
        float bv = bias[gcol];
        #pragma unroll
        for (int i = 0; i < 4; ++i) {
            #pragma unroll
            for (int r = 0; r < 4; ++r) {
                int grow = bm + wm + i * 16 + crow + r;
                if (grow < M) {
                    float val = acc[i][j][r] + bv;
                    if (OUT_BF16)
                        ((ushort*)Cv)[(size_t)grow * N + gcol] = f2bf(val);
                    else
                        ((float*)Cv)[(size_t)grow * N + gcol] = val;
                }
            }
        }
    }
}

// ---------------------------------------------------------------------------
// fp32 tiled GEMM (kept for the final out-projection, precision headroom)
// ---------------------------------------------------------------------------
__global__ __launch_bounds__(256) void gemm128(
    const float* __restrict__ A, const float* __restrict__ B,
    const float* __restrict__ bias, float* __restrict__ C,
    int M, int N)
{
    constexpr int K = 256;
    __shared__ float Asm[8][128];
    __shared__ float Bsm[8][128];

    const int t  = threadIdx.x;
    const int bm = blockIdx.x * 128;
    const int bn = blockIdx.y * 128;
    const int tx = t & 15;
    const int ty = t >> 4;

    const int arow = t >> 1;
    const int akv  = (t & 1) * 4;
    const int brow = t >> 5;
    const int bcol = (t & 31) * 4;

    const bool arowok = (bm + arow) < M;
    const float* Aptr = A + (size_t)(bm + arow) * K + akv;
    const float* Bptr = B + (size_t)brow * N + bn + bcol;

    float4 acc[2][2][4];
    #pragma unroll
    for (int i = 0; i < 2; ++i)
        #pragma unroll
        for (int j = 0; j < 2; ++j)
            #pragma unroll
            for (int e = 0; e < 4; ++e)
                acc[i][j][e] = make_float4(0.f, 0.f, 0.f, 0.f);

    for (int kt = 0; kt < K; kt += 8) {
        float4 af = arowok ? *(const float4*)(Aptr + kt)
                           : make_float4(0.f, 0.f, 0.f, 0.f);
        float4 bf = *(const float4*)(Bptr + (size_t)kt * N);

        __syncthreads();
        Asm[akv + 0][arow] = af.x;
        Asm[akv + 1][arow] = af.y;
        Asm[akv + 2][arow] = af.z;
        Asm[akv + 3][arow] = af.w;
        *(float4*)&Bsm[brow][bcol] = bf;
        __syncthreads();

        #pragma unroll
        for (int k = 0; k < 8; ++k) {
            float4 a0 = *(const float4*)&Asm[k][ty * 4];
            float4 a1 = *(const float4*)&Asm[k][ty * 4 + 64];
            float4 b0 = *(const float4*)&Bsm[k][tx * 4];
            float4 b1 = *(const float4*)&Bsm[k][tx * 4 + 64];
            float ar[8] = {a0.x, a0.y, a0.z, a0.w, a1.x, a1.y, a1.z, a1.w};
            #pragma unroll
            for (int i = 0; i < 2; ++i) {
                #pragma unroll
                for (int e = 0; e < 4; ++e) {
                    float a = ar[i * 4 + e];
                    FMA4(acc[i][0][e], a, b0);
                    FMA4(acc[i][1][e], a, b1);
                }
            }
        }
    }

    float4 bias0 = *(const float4*)(bias + bn + tx * 4);
    float4 bias1 = *(const float4*)(bias + bn + 64 + tx * 4);

    #pragma unroll
    for (int i = 0; i < 2; ++i) {
        #pragma unroll
        for (int e = 0; e < 4; ++e) {
            int row = bm + i * 64 + ty * 4 + e;
            if (row < M) {
                float4 r0 = acc[i][0][e];
                r0.x += bias0.x; r0.y += bias0.y; r0.z += bias0.z; r0.w += bias0.w;
                *(float4*)(C + (size_t)row * N + bn + tx * 4) = r0;
                float4 r1 = acc[i][1][e];
                r1.x += bias1.x; r1.y += bias1.y; r1.z += bias1.z; r1.w += bias1.w;
                *(float4*)(C + (size_t)row * N + bn + 64 + tx * 4) = r1;
            }
        }
    }
}

// ---------------------------------------------------------------------------
// softmax over rows of 32 (in-place capable)
// ---------------------------------------------------------------------------
__global__ __launch_bounds__(256) void softmax32(
    const float* __restrict__ in, float* __restrict__ out, int rows)
{
    int r = blockIdx.x * blockDim.x + threadIdx.x;
    if (r >= rows) return;
    const float* p = in + (size_t)r * 32;
    float v[32];
    #pragma unroll
    for (int i = 0; i < 8; ++i)
        *(float4*)&v[i * 4] = *(const float4*)(p + i * 4);
    float m = v[0];
    #pragma unroll
    for (int i = 1; i < 32; ++i) m = fmaxf(m, v[i]);
    float s = 0.f;
    #pragma unroll
    for (int i = 0; i < 32; ++i) { v[i] = __expf(v[i] - m); s += v[i]; }
    float inv = 1.f / s;
    float* q = out + (size_t)r * 32;
    #pragma unroll
    for (int i = 0; i < 8; ++i) {
        float4 wv = make_float4(v[i*4] * inv, v[i*4+1] * inv, v[i*4+2] * inv, v[i*4+3] * inv);
        *(float4*)(q + i * 4) = wv;
    }
}

// ---------------------------------------------------------------------------
// Deformable sampling + aggregation, bf16 v.
// 4 threads per (b,q,h); thread st owns channels [st*8, st*8+8) (16B gathers)
// and points [st*8, st*8+8) for width-4 shuffle broadcast.
// ---------------------------------------------------------------------------
__global__ __launch_bounds__(256) void sampler4(
    const ushort* __restrict__ v,    // (BS, LTOT, 256) bf16
    const float* __restrict__ off,   // (BS*NQ, 8, 4, 8, 2)
    const float* __restrict__ aw,    // (BS*NQ, 8, 32) softmaxed
    const float* __restrict__ ref,   // (BS*NQ, 4, 2)
    float* __restrict__ agg)         // (BS*NQ, 256) fp32
{
    const int tid = threadIdx.x;
    const int g = blockIdx.x * 64 + (tid >> 2);   // (b*NQ+q)*8 + h
    const int st = tid & 3;
    const int h = g & 7;
    const int bq = g >> 3;
    const int b = bq >> 12;   // NQ = 4096

    float o[16];
    {
        const float* offp = off + (size_t)bq * 512 + h * 64 + st * 16;
        #pragma unroll
        for (int i = 0; i < 4; ++i)
            *(float4*)&o[i * 4] = *(const float4*)(offp + i * 4);
    }
    float a8[8];
    {
        const float* awp = aw + (size_t)bq * 256 + h * 32 + st * 8;
        *(float4*)&a8[0] = *(const float4*)(awp);
        *(float4*)&a8[4] = *(const float4*)(awp + 4);
    }
    float rf[8];
    *(float4*)&rf[0] = *(const float4*)(ref + (size_t)bq * 8);
    *(float4*)&rf[4] = *(const float4*)(ref + (size_t)bq * 8 + 4);

    const ushort* vb = v + (size_t)b * LTOT * EMB + h * 32 + st * 8;

    const int LW[4] = {160, 80, 40, 20};
    const int LH[4] = {92, 46, 23, 12};
    const int LS[4] = {0, 14720, 18400, 19320};

    float acc[8] = {0.f, 0.f, 0.f, 0.f, 0.f, 0.f, 0.f, 0.f};

    #pragma unroll
    for (int k = 0; k < 32; ++k) {
        const int l = k >> 3;
        const int W = LW[l], Hh = LH[l], S = LS[l];
        const int src = k >> 3;          // careful: owner lane of point k
        const int idx = k & 7;
        // point k is held by lane (k>>3) at local index (k&7)
        float awk = __shfl(a8[idx], k >> 3, 4);
        float ox  = __shfl(o[2 * idx], k >> 3, 4);
        float oy  = __shfl(o[2 * idx + 1], k >> 3, 4);
        (void)src;

        float px = fmaf(rf[2 * l], (float)W, ox) - 0.5f;
        float py = fmaf(rf[2 * l + 1], (float)Hh, oy) - 0.5f;
        float x0f = floorf(px), y0f = floorf(py);
        float wx = px - x0f, wy = py - y0f;
        int x0 = (int)x0f, y0 = (int)y0f;
        int x1 = x0 + 1, y1 = y0 + 1;

        float vx0 = (x0 >= 0 && x0 < W) ? 1.f : 0.f;
        float vx1 = (x1 >= 0 && x1 < W) ? 1.f : 0.f;
        float vy0 = (y0 >= 0 && y0 < Hh) ? 1.f : 0.f;
        float vy1 = (y1 >= 0 && y1 < Hh) ? 1.f : 0.f;
        int cx0 = min(max(x0, 0), W - 1);
        int cx1 = min(max(x1, 0), W - 1);
        int cy0 = min(max(y0, 0), Hh - 1);
        int cy1 = min(max(y1, 0), Hh - 1);

        float w00 = (1.f - wx) * (1.f - wy) * vx0 * vy0 * awk;
        float w10 = wx * (1.f - wy) * vx1 * vy0 * awk;
        float w01 = (1.f - wx) * wy * vx0 * vy1 * awk;
        float w11 = wx * wy * vx1 * vy1 * awk;

        uint4 c00 = *(const uint4*)(vb + (size_t)(S + cy0 * W + cx0) * EMB);
        uint4 c10 = *(const uint4*)(vb + (size_t)(S + cy0 * W + cx1) * EMB);
        uint4 c01 = *(const uint4*)(vb + (size_t)(S + cy1 * W + cx0) * EMB);
        uint4 c11 = *(const uint4*)(vb + (size_t)(S + cy1 * W + cx1) * EMB);

        #define ACC8(w_, c_) \
            acc[0] = fmaf(w_, bflo(c_.x), acc[0]); acc[1] = fmaf(w_, bfhi(c_.x), acc[1]); \
            acc[2] = fmaf(w_, bflo(c_.y), acc[2]); acc[3] = fmaf(w_, bfhi(c_.y), acc[3]); \
            acc[4] = fmaf(w_, bflo(c_.z), acc[4]); acc[5] = fmaf(w_, bfhi(c_.z), acc[5]); \
            acc[6] = fmaf(w_, bflo(c_.w), acc[6]); acc[7] = fmaf(w_, bfhi(c_.w), acc[7]);
        ACC8(w00, c00);
        ACC8(w10, c10);
        ACC8(w01, c01);
        ACC8(w11, c11);
        #undef ACC8
    }

    float* ap = agg + (size_t)bq * 256 + h * 32 + st * 8;
    *(float4*)ap       = make_float4(acc[0], acc[1], acc[2], acc[3]);
    *(float4*)(ap + 4) = make_float4(acc[4], acc[5], acc[6], acc[7]);
}

// ---------------------------------------------------------------------------
// Launch
// ---------------------------------------------------------------------------
extern "C" void kernel_launch(void* const* d_in, const int* in_sizes, int n_in,
                              void* d_out, int out_size, void* d_ws, size_t ws_size,
                              hipStream_t stream) {
    const float* query  = (const float*)d_in[0];
    const float* value  = (const float*)d_in[1];
    const float* refpts = (const float*)d_in[2];
    const float* W_off  = (const float*)d_in[4];
    const float* b_off  = (const float*)d_in[5];
    const float* W_attn = (const float*)d_in[6];
    const float* b_attn = (const float*)d_in[7];
    const float* W_val  = (const float*)d_in[8];
    const float* b_val  = (const float*)d_in[9];
    const float* W_out  = (const float*)d_in[10];
    const float* b_out  = (const float*)d_in[11];
    float* out = (float*)d_out;

    char* ws = (char*)d_ws;
    // layout (bytes):
    //   v_bf    @ 0           60,096,512   (117376 x 256 bf16)
    //   val_bf  @ 60,096,512  60,096,512   (117376 x 256 bf16) -- agg aliases
    //   q_bf    @ 120,193,024 12,582,912   (24576 x 256 bf16)
    //   off_b   @ 132,775,936 50,331,648   (24576 x 512 f32)
    //   attn_b  @ 183,107,584 25,165,824   (24576 x 256 f32)
    //   Wvt     @ 208,273,408    131,072
    //   Woft    @ 208,404,480    262,144
    //   Wat     @ 208,666,624    131,072
    ushort* v_bf   = (ushort*)(ws);
    ushort* val_bf = (ushort*)(ws + 60096512ull);
    float*  agg    = (float*) (ws + 60096512ull);   // alias: val_bf dead by then
    ushort* q_bf   = (ushort*)(ws + 120193024ull);
    float*  off_b  = (float*) (ws + 132775936ull);
    float*  attn_b = (float*) (ws + 183107584ull);
    ushort* Wvt    = (ushort*)(ws + 208273408ull);
    ushort* Woft   = (ushort*)(ws + 208404480ull);
    ushort* Wat    = (ushort*)(ws + 208666624ull);

    // casts
    cast_bf16<<<(ROWS_VP * EMB / 8) / 256, 256, 0, stream>>>(
        value, val_bf, ROWS_V * EMB, ROWS_VP * EMB);
    cast_bf16<<<(ROWS_Q * EMB / 8) / 256, 256, 0, stream>>>(
        query, q_bf, ROWS_Q * EMB, ROWS_Q * EMB);
    cast_t<<<(256 * 256) / 256, 256, 0, stream>>>(W_val, Wvt, 256);
    cast_t<<<(256 * 512) / 256, 256, 0, stream>>>(W_off, Woft, 512);
    cast_t<<<(256 * 256) / 256, 256, 0, stream>>>(W_attn, Wat, 256);

    // 1. v = value @ W_val + b_val  -> bf16
    gemm_bt<true><<<dim3(ROWS_VP / 128, 2), 256, 0, stream>>>(
        val_bf, Wvt, b_val, v_bf, ROWS_V, 256);

    // 2. off / attn logits
    gemm_bt<false><<<dim3(ROWS_Q / 128, 4), 256, 0, stream>>>(
        q_bf, Woft, b_off, off_b, ROWS_Q, 512);
    gemm_bt<false><<<dim3(ROWS_Q / 128, 2), 256, 0, stream>>>(
        q_bf, Wat, b_attn, attn_b, ROWS_Q, 256);

    // 3. softmax
    softmax32<<<(ROWS_Q * NH) / 256, 256, 0, stream>>>(
        attn_b, attn_b, ROWS_Q * NH);

    // 4. sampling + aggregation (agg overwrites val_bf region — safe)
    sampler4<<<(ROWS_Q * NH) / 64, 256, 0, stream>>>(
        v_bf, off_b, attn_b, refpts, agg);

    // 5. out = agg @ W_out + b_out  (fp32 for precision headroom)
    gemm128<<<dim3(ROWS_Q / 128, 2), 256, 0, stream>>>(
        agg, W_out, b_out, out, ROWS_Q, 256);
}

// Round 3
// 416.379 us; speedup vs baseline: 1.7379x; 1.1600x over previous
//
#include <hip/hip_runtime.h>
#include <stdint.h>

// Problem constants
#define BS 6
#define NQ 4096
#define NH 8
#define EMB 256
#define LTOT 19560
#define ROWS_V 117360
#define ROWS_VP 117376          // padded to 917*128
#define ROWS_Q 24576            // 192*128

typedef __attribute__((ext_vector_type(8))) short bf16x8;
typedef __attribute__((ext_vector_type(4))) float floatx4;
typedef __attribute__((ext_vector_type(8))) unsigned short ushort8v;

__device__ __forceinline__ ushort f2bf(float f) {
    union { float f; uint32_t i; } c; c.f = f;
    uint32_t r = c.i + 0x7FFFu + ((c.i >> 16) & 1u);   // round-to-nearest-even
    return (ushort)(r >> 16);
}
__device__ __forceinline__ float bflo(uint32_t u) {
    union { uint32_t i; float f; } c; c.i = u << 16; return c.f;
}
__device__ __forceinline__ float bfhi(uint32_t u) {
    union { uint32_t i; float f; } c; c.i = u & 0xFFFF0000u; return c.f;
}

__device__ __forceinline__ void gll16(const ushort* g, ushort* l) {
    __builtin_amdgcn_global_load_lds(
        (const __attribute__((address_space(1))) void*)g,
        (__attribute__((address_space(3))) void*)l, 16, 0, 0);
}

// ---------------------------------------------------------------------------
// fp32 -> bf16 cast (row-contiguous), 8 elems/thread
// ---------------------------------------------------------------------------
__global__ __launch_bounds__(256) void cast_bf16(
    const float* __restrict__ in, ushort* __restrict__ out, int n)
{
    int i = (blockIdx.x * 256 + threadIdx.x) * 8;
    if (i >= n) return;
    float4 f0 = *(const float4*)(in + i);
    float4 f1 = *(const float4*)(in + i + 4);
    ushort8v r;
    r[0] = f2bf(f0.x); r[1] = f2bf(f0.y); r[2] = f2bf(f0.z); r[3] = f2bf(f0.w);
    r[4] = f2bf(f1.x); r[5] = f2bf(f1.y); r[6] = f2bf(f1.z); r[7] = f2bf(f1.w);
    *(ushort8v*)(out + i) = r;
}

// ---------------------------------------------------------------------------
// W (K=256 x N) fp32  ->  Wt (N x 256) bf16   (tiny matrices)
// ---------------------------------------------------------------------------
__global__ __launch_bounds__(256) void cast_t(
    const float* __restrict__ W, ushort* __restrict__ Wt, int N_)
{
    int id = blockIdx.x * 256 + threadIdx.x;
    if (id >= 256 * N_) return;
    int n = id >> 8;         // / 256 (K = 256)
    int k = id & 255;
    Wt[id] = f2bf(W[(size_t)k * N_ + n]);
}

__global__ __launch_bounds__(768) void bias_concat(
    const float* __restrict__ b_off, const float* __restrict__ b_attn,
    float* __restrict__ bcat)
{
    int i = threadIdx.x;
    bcat[i] = (i < 512) ? b_off[i] : b_attn[i - 512];
}

// ---------------------------------------------------------------------------
// Fused value GEMM: v = value(fp32) @ Wvt^T + b_val -> bf16
// Block: 512 threads = 8 waves (2x4), tile 128(M) x 256(N=full), BK=32.
// A: fp32 global -> reg cast -> LDS.  B: all 256 rows staged via gll16.
// ---------------------------------------------------------------------------
__global__ __launch_bounds__(512) void vgemm(
    const float* __restrict__ A,     // ROWS_V x 256 fp32
    const ushort* __restrict__ Bt,   // 256 x 256 bf16
    const float* __restrict__ bias,  // 256
    ushort* __restrict__ C)          // ROWS_VP x 256 bf16
{
    constexpr int K = 256, N = 256, M = ROWS_V;
    __shared__ ushort As[128 * 32];
    __shared__ ushort Bs[256 * 32];

    const int t = threadIdx.x;
    const int w = t >> 6;
    const int lane = t & 63;
    const int bm = blockIdx.x * 128;
    const int wm = (w >> 2) * 64;
    const int wn = (w & 3) * 64;

    // A staging: thread t -> row t>>2 (0..127), cols (t&3)*8 .. +8
    const int arow = t >> 2;
    const int acol = (t & 3) * 8;
    const bool rowok = (bm + arow) < M;
    const float* Ap = A + (size_t)(bm + arow) * K + acol;
    ushort* Asw = &As[arow * 32 + acol];

    // B staging: wave w stages rows [32w, 32w+32) in two 16-row chunks
    const int srow = lane >> 2;
    const int scol = (lane & 3) * 8;
    const ushort* Bg0 = Bt + (size_t)(w * 32 + srow) * K + scol;
    const ushort* Bg1 = Bt + (size_t)(w * 32 + 16 + srow) * K + scol;
    ushort* Bl0 = &Bs[(w * 32) * 32];
    ushort* Bl1 = &Bs[(w * 32 + 16) * 32];

    const ushort* apt = &As[(wm + (lane & 15)) * 32 + (lane >> 4) * 8];
    const ushort* bpt = &Bs[(wn + (lane & 15)) * 32 + (lane >> 4) * 8];

    floatx4 acc[4][4] = {};

    for (int kt = 0; kt < K; kt += 32) {
        float4 f0, f1;
        if (rowok) {
            f0 = *(const float4*)(Ap + kt);
            f1 = *(const float4*)(Ap + kt + 4);
        } else {
            f0 = make_float4(0.f, 0.f, 0.f, 0.f);
            f1 = f0;
        }
        __syncthreads();   // previous iter's fragment reads done
        gll16(Bg0 + kt, Bl0);
        gll16(Bg1 + kt, Bl1);
        ushort8v u;
        u[0] = f2bf(f0.x); u[1] = f2bf(f0.y); u[2] = f2bf(f0.z); u[3] = f2bf(f0.w);
        u[4] = f2bf(f1.x); u[5] = f2bf(f1.y); u[6] = f2bf(f1.z); u[7] = f2bf(f1.w);
        *(ushort8v*)Asw = u;
        __syncthreads();   // staging visible (drains vmcnt + lgkmcnt)

        bf16x8 a[4], b[4];
        #pragma unroll
        for (int i = 0; i < 4; ++i) {
            a[i] = *(const bf16x8*)(apt + i * 16 * 32);
            b[i] = *(const bf16x8*)(bpt + i * 16 * 32);
        }
        #pragma unroll
        for (int i = 0; i < 4; ++i)
            #pragma unroll
            for (int j = 0; j < 4; ++j)
                acc[i][j] = __builtin_amdgcn_mfma_f32_16x16x32_bf16(
                    a[i], b[j], acc[i][j], 0, 0, 0);
    }

    const int crow = (lane >> 4) * 4;
    const int ccol = lane & 15;
    #pragma unroll
    for (int j = 0; j < 4; ++j) {
        int gcol = wn + j * 16 + ccol;
        float bv = bias[gcol];
        #pragma unroll
        for (int i = 0; i < 4; ++i) {
            #pragma unroll
            for (int r = 0; r < 4; ++r) {
                int grow = bm + wm + i * 16 + crow + r;
                if (grow < M)
                    C[(size_t)grow * N + gcol] = f2bf(acc[i][j][r] + bv);
            }
        }
    }
}

// ---------------------------------------------------------------------------
// bf16 MFMA GEMM (m97 structure): C[M,N] = A[M,256] @ Bt[N,256]^T + bias
// fp32 output. 128x128 tile, 256 threads = 4 waves.
// ---------------------------------------------------------------------------
__global__ __launch_bounds__(256) void gemm_bt(
    const ushort* __restrict__ A,    // Mpad x 256 bf16
    const ushort* __restrict__ Bt,   // N x 256 bf16
    const float* __restrict__ bias,  // N
    float* __restrict__ C, int M, int N)
{
    constexpr int K = 256;
    __shared__ ushort As[128 * 32];
    __shared__ ushort Bs[128 * 32];

    const int t = threadIdx.x;
    const int w = t >> 6;
    const int lane = t & 63;
    const int bm = blockIdx.x * 128;
    const int bn = blockIdx.y * 128;
    const int wm = (w >> 1) * 64;
    const int wn = (w & 1) * 64;

    floatx4 acc[4][4] = {};

    const int srow = lane >> 2;
    const int scol = (lane & 3) * 8;
    const ushort* Ag0 = A + (size_t)(bm + (w * 2 + 0) * 16 + srow) * K + scol;
    const ushort* Ag1 = A + (size_t)(bm + (w * 2 + 1) * 16 + srow) * K + scol;
    const ushort* Bg0 = Bt + (size_t)(bn + (w * 2 + 0) * 16 + srow) * K + scol;
    const ushort* Bg1 = Bt + (size_t)(bn + (w * 2 + 1) * 16 + srow) * K + scol;
    ushort* Al0 = &As[(w * 2 + 0) * 512];
    ushort* Al1 = &As[(w * 2 + 1) * 512];
    ushort* Bl0 = &Bs[(w * 2 + 0) * 512];
    ushort* Bl1 = &Bs[(w * 2 + 1) * 512];

    const ushort* apt = &As[(wm + (lane & 15)) * 32 + (lane >> 4) * 8];
    const ushort* bpt = &Bs[(wn + (lane & 15)) * 32 + (lane >> 4) * 8];

    for (int kt = 0; kt < K; kt += 32) {
        __syncthreads();
        gll16(Ag0 + kt, Al0);
        gll16(Ag1 + kt, Al1);
        gll16(Bg0 + kt, Bl0);
        gll16(Bg1 + kt, Bl1);
        __syncthreads();

        bf16x8 a[4], b[4];
        #pragma unroll
        for (int i = 0; i < 4; ++i) {
            a[i] = *(const bf16x8*)(apt + i * 16 * 32);
            b[i] = *(const bf16x8*)(bpt + i * 16 * 32);
        }
        #pragma unroll
        for (int i = 0; i < 4; ++i)
            #pragma unroll
            for (int j = 0; j < 4; ++j)
                acc[i][j] = __builtin_amdgcn_mfma_f32_16x16x32_bf16(
                    a[i], b[j], acc[i][j], 0, 0, 0);
    }

    const int crow = (lane >> 4) * 4;
    const int ccol = lane & 15;
    #pragma unroll
    for (int j = 0; j < 4; ++j) {
        int gcol = bn + wn + j * 16 + ccol;
        float bv = bias[gcol];
        #pragma unroll
        for (int i = 0; i < 4; ++i) {
            #pragma unroll
            for (int r = 0; r < 4; ++r) {
                int grow = bm + wm + i * 16 + crow + r;
                if (grow < M)
                    C[(size_t)grow * N + gcol] = acc[i][j][r] + bv;
            }
        }
    }
}

// ---------------------------------------------------------------------------
// Deformable sampling + aggregation with fused softmax, bf16 v, bf16 agg out.
// 4 threads per (b,q,h); thread st owns channels [st*8, st*8+8) and points
// [st*8, st*8+8) for width-4 shuffle broadcast.
// qp layout per row (768): [0:512) offsets, [512:768) attn logits.
// ---------------------------------------------------------------------------
__global__ __launch_bounds__(256) void sampler4(
    const ushort* __restrict__ v,    // (BS, LTOT, 256) bf16
    const float* __restrict__ qp,    // (BS*NQ, 768)
    const float* __restrict__ ref,   // (BS*NQ, 4, 2)
    ushort* __restrict__ agg)        // (BS*NQ, 256) bf16
{
    const int tid = threadIdx.x;
    const int g = blockIdx.x * 64 + (tid >> 2);   // (b*NQ+q)*8 + h
    const int st = tid & 3;
    const int h = g & 7;
    const int bq = g >> 3;
    const int b = bq >> 12;   // NQ = 4096

    float o[16];
    {
        const float* offp = qp + (size_t)bq * 768 + h * 64 + st * 16;
        #pragma unroll
        for (int i = 0; i < 4; ++i)
            *(float4*)&o[i * 4] = *(const float4*)(offp + i * 4);
    }
    // fused softmax over 32 logits (8 per lane, width-4 group)
    float a8[8];
    {
        const float* lp = qp + (size_t)bq * 768 + 512 + h * 32 + st * 8;
        *(float4*)&a8[0] = *(const float4*)(lp);
        *(float4*)&a8[4] = *(const float4*)(lp + 4);
        float m = a8[0];
        #pragma unroll
        for (int i = 1; i < 8; ++i) m = fmaxf(m, a8[i]);
        m = fmaxf(m, __shfl_xor(m, 1, 4));
        m = fmaxf(m, __shfl_xor(m, 2, 4));
        float s = 0.f;
        #pragma unroll
        for (int i = 0; i < 8; ++i) { a8[i] = __expf(a8[i] - m); s += a8[i]; }
        s += __shfl_xor(s, 1, 4);
        s += __shfl_xor(s, 2, 4);
        float inv = 1.f / s;
        #pragma unroll
        for (int i = 0; i < 8; ++i) a8[i] *= inv;
    }
    float rf[8];
    *(float4*)&rf[0] = *(const float4*)(ref + (size_t)bq * 8);
    *(float4*)&rf[4] = *(const float4*)(ref + (size_t)bq * 8 + 4);

    const ushort* vb = v + (size_t)b * LTOT * EMB + h * 32 + st * 8;

    const int LW[4] = {160, 80, 40, 20};
    const int LH[4] = {92, 46, 23, 12};
    const int LS[4] = {0, 14720, 18400, 19320};

    float acc[8] = {0.f, 0.f, 0.f, 0.f, 0.f, 0.f, 0.f, 0.f};

    #pragma unroll
    for (int k = 0; k < 32; ++k) {
        const int l = k >> 3;
        const int W = LW[l], Hh = LH[l], S = LS[l];
        const int idx = k & 7;
        float awk = __shfl(a8[idx], k >> 3, 4);
        float ox  = __shfl(o[2 * idx], k >> 3, 4);
        float oy  = __shfl(o[2 * idx + 1], k >> 3, 4);

        float px = fmaf(rf[2 * l], (float)W, ox) - 0.5f;
        float py = fmaf(rf[2 * l + 1], (float)Hh, oy) - 0.5f;
        float x0f = floorf(px), y0f = floorf(py);
        float wx = px - x0f, wy = py - y0f;
        int x0 = (int)x0f, y0 = (int)y0f;
        int x1 = x0 + 1, y1 = y0 + 1;

        float vx0 = (x0 >= 0 && x0 < W) ? 1.f : 0.f;
        float vx1 = (x1 >= 0 && x1 < W) ? 1.f : 0.f;
        float vy0 = (y0 >= 0 && y0 < Hh) ? 1.f : 0.f;
        float vy1 = (y1 >= 0 && y1 < Hh) ? 1.f : 0.f;
        int cx0 = min(max(x0, 0), W - 1);
        int cx1 = min(max(x1, 0), W - 1);
        int cy0 = min(max(y0, 0), Hh - 1);
        int cy1 = min(max(y1, 0), Hh - 1);

        float w00 = (1.f - wx) * (1.f - wy) * vx0 * vy0 * awk;
        float w10 = wx * (1.f - wy) * vx1 * vy0 * awk;
        float w01 = (1.f - wx) * wy * vx0 * vy1 * awk;
        float w11 = wx * wy * vx1 * vy1 * awk;

        uint4 c00 = *(const uint4*)(vb + (size_t)(S + cy0 * W + cx0) * EMB);
        uint4 c10 = *(const uint4*)(vb + (size_t)(S + cy0 * W + cx1) * EMB);
        uint4 c01 = *(const uint4*)(vb + (size_t)(S + cy1 * W + cx0) * EMB);
        uint4 c11 = *(const uint4*)(vb + (size_t)(S + cy1 * W + cx1) * EMB);

        #define ACC8(w_, c_) \
            acc[0] = fmaf(w_, bflo(c_.x), acc[0]); acc[1] = fmaf(w_, bfhi(c_.x), acc[1]); \
            acc[2] = fmaf(w_, bflo(c_.y), acc[2]); acc[3] = fmaf(w_, bfhi(c_.y), acc[3]); \
            acc[4] = fmaf(w_, bflo(c_.z), acc[4]); acc[5] = fmaf(w_, bfhi(c_.z), acc[5]); \
            acc[6] = fmaf(w_, bflo(c_.w), acc[6]); acc[7] = fmaf(w_, bfhi(c_.w), acc[7]);
        ACC8(w00, c00);
        ACC8(w10, c10);
        ACC8(w01, c01);
        ACC8(w11, c11);
        #undef ACC8
    }

    ushort8v r;
    #pragma unroll
    for (int i = 0; i < 8; ++i) r[i] = f2bf(acc[i]);
    *(ushort8v*)(agg + (size_t)bq * 256 + h * 32 + st * 8) = r;
}

// ---------------------------------------------------------------------------
// Launch
// ---------------------------------------------------------------------------
extern "C" void kernel_launch(void* const* d_in, const int* in_sizes, int n_in,
                              void* d_out, int out_size, void* d_ws, size_t ws_size,
                              hipStream_t stream) {
    const float* query  = (const float*)d_in[0];
    const float* value  = (const float*)d_in[1];
    const float* refpts = (const float*)d_in[2];
    const float* W_off  = (const float*)d_in[4];
    const float* b_off  = (const float*)d_in[5];
    const float* W_attn = (const float*)d_in[6];
    const float* b_attn = (const float*)d_in[7];
    const float* W_val  = (const float*)d_in[8];
    const float* b_val  = (const float*)d_in[9];
    const float* W_out  = (const float*)d_in[10];
    const float* b_out  = (const float*)d_in[11];
    float* out = (float*)d_out;

    char* ws = (char*)d_ws;
    // layout (bytes):
    ushort* v_bf   = (ushort*)(ws);                     // 117376x256 bf16 = 60,096,512
    ushort* q_bf   = (ushort*)(ws + 60096512ull);       // 24576x256 bf16 = 12,582,912
    float*  qp     = (float*) (ws + 72679424ull);       // 24576x768 f32  = 75,497,472
    ushort* agg_bf = (ushort*)(ws + 148176896ull);      // 24576x256 bf16 = 12,582,912
    ushort* Wvt    = (ushort*)(ws + 160759808ull);      // 131,072
    ushort* Wq     = (ushort*)(ws + 160890880ull);      // 768x256 bf16 = 393,216
    ushort* Wot    = (ushort*)(ws + 161284096ull);      // 131,072
    float*  bcat   = (float*) (ws + 161415168ull);      // 3,072

    // weight preprocessing
    cast_t<<<(256 * 256) / 256, 256, 0, stream>>>(W_val, Wvt, 256);
    cast_t<<<(256 * 512) / 256, 256, 0, stream>>>(W_off, Wq, 512);
    cast_t<<<(256 * 256) / 256, 256, 0, stream>>>(W_attn, Wq + 512 * 256, 256);
    cast_t<<<(256 * 256) / 256, 256, 0, stream>>>(W_out, Wot, 256);
    bias_concat<<<1, 768, 0, stream>>>(b_off, b_attn, bcat);
    cast_bf16<<<(ROWS_Q * EMB / 8) / 256, 256, 0, stream>>>(
        query, q_bf, ROWS_Q * EMB);

    // 1. v = value @ W_val + b_val -> bf16 (fused fp32 read + cast)
    vgemm<<<ROWS_VP / 128, 512, 0, stream>>>(value, Wvt, b_val, v_bf);

    // 2. qp = query @ [W_off | W_attn] + [b_off | b_attn]  (N=768)
    gemm_bt<<<dim3(ROWS_Q / 128, 6), 256, 0, stream>>>(
        q_bf, Wq, bcat, qp, ROWS_Q, 768);

    // 3. sampling + softmax + aggregation -> bf16 agg
    sampler4<<<(ROWS_Q * NH) / 64, 256, 0, stream>>>(
        v_bf, qp, refpts, agg_bf);

    // 4. out = agg @ W_out + b_out (bf16 MFMA, fp32 out)
    gemm_bt<<<dim3(ROWS_Q / 128, 2), 256, 0, stream>>>(
        agg_bf, Wot, b_out, out, ROWS_Q, 256);
}